// Round 15
// baseline (885.321 us; speedup 1.0000x reference)
//
#include <hip/hip_runtime.h>

#define TT 1024
#define DD 32
#define HH 64

typedef __fp16 h2v __attribute__((ext_vector_type(2)));
typedef _Float16 f16x8 __attribute__((ext_vector_type(8)));
typedef float f32x4 __attribute__((ext_vector_type(4)));

struct __attribute__((aligned(16))) H4 { h2v p[4]; };

__device__ __forceinline__ h2v pk(float a, float b) {
    return __builtin_amdgcn_cvt_pkrtz(a, b);
}
__device__ __forceinline__ float fsig(float x) {
    float e = __builtin_amdgcn_exp2f(-1.4426950408889634f * x);
    return __builtin_amdgcn_rcpf(1.0f + e);
}
__device__ __forceinline__ float ftanh(float x) {
    float e = __builtin_amdgcn_exp2f(2.885390081777927f * x);
    return 1.0f - 2.0f * __builtin_amdgcn_rcpf(1.0f + e);
}
// LDS-only barrier: orders ds ops, leaves global prefetches in flight.
__device__ __forceinline__ void bar_lds() {
    asm volatile("s_waitcnt lgkmcnt(0)\n\ts_barrier" ::: "memory");
}
__device__ __forceinline__ float pick4(f32x4 c, bool s0, bool s1) {
    float lo = s0 ? c[1] : c[0];
    float hi = s0 ? c[3] : c[2];
    return s1 ? hi : lo;
}
__device__ __forceinline__ f16x8 load_afrag(const float* p) {
    float4 f0 = *(const float4*)p;
    float4 f1 = *(const float4*)(p + 4);
    H4 t;
    t.p[0] = pk(f0.x, f0.y); t.p[1] = pk(f0.z, f0.w);
    t.p[2] = pk(f1.x, f1.y); t.p[3] = pk(f1.z, f1.w);
    return __builtin_bit_cast(f16x8, t);
}
#define MFMA16(A, B, C) __builtin_amdgcn_mfma_f32_16x16x32_f16(A, B, C, 0, 0, 0)

// ---------------------------------------------------------------------------
// 64 blocks x 256 threads (4 waves); block = 4 batch elements.
// Wave js (0..3) computes BOTH layers for its 16-j slice: h1(t) and h2(t-1)
// (same software-pipeline skew as R12, co-located in one wave).
//   - h1 B-fragments (chunks 1,2) are read once, used by both layers' MFMAs
//   - 4 barrier participants instead of 8
//   - weight fragments are MFMA-A-operands only -> AGPR-resident at no cost
// LDS per parity: 5 chunks x [batch4][quad4][8 f16]:
//   chunk 0 = x(t), chunks 1,2 = h1(t-1), chunks 3,4 = h2(t-2)
// B cols = 4 batches x 4 reps (col&3 = batch). C layout (m89): col=lane&15,
// row=quad*4+reg -> lane owns unique cells (j=js*16+quad*4+rsel, batch=lane&3)
// for BOTH layers. Wave 3 also stages x(t+1) (2-deep register ring).
// ---------------------------------------------------------------------------
__global__ __launch_bounds__(256) void lstm2_m4(
    const float* __restrict__ x,
    const float* __restrict__ w_ih_l0, const float* __restrict__ w_hh_l0,
    const float* __restrict__ b_ih_l0, const float* __restrict__ b_hh_l0,
    const float* __restrict__ w_ih_l1, const float* __restrict__ w_hh_l1,
    const float* __restrict__ b_ih_l1, const float* __restrict__ b_hh_l1,
    const float* __restrict__ w_fc,   const float* __restrict__ b_fc,
    float* __restrict__ out)
{
    const int bbase = blockIdx.x * 4;
    const int tid  = threadIdx.x;
    const int wave = tid >> 6;          // = js
    const int lane = tid & 63;
    const int js   = wave;
    const int quad = lane >> 4;
    const int bb   = lane & 3;
    const int rsel = (lane >> 2) & 3;
    const int jj   = js*16 + quad*4 + rsel;
    const int mrow = lane & 15;

    __shared__ __attribute__((aligned(16))) __fp16 buf[1280];  // [2][5][4][4][8]
    {
        int* bi = (int*)buf;
        bi[tid] = 0; bi[256 + tid] = 0;
        if (tid < 128) bi[512 + tid] = 0;
    }

    // ---- weights (MFMA A-fragments; AGPR-safe) + biases ----
    f16x8 A1[12], A2[16];
    float b10, b11, b12, b13, b20, b21, b22, b23;
    #pragma unroll
    for (int q = 0; q < 4; ++q) {
        const int g = q*64 + js*16 + mrow;
        A1[q*3 + 0] = load_afrag(w_ih_l0 + (size_t)g*DD + quad*8);
        A1[q*3 + 1] = load_afrag(w_hh_l0 + (size_t)g*HH + quad*8);
        A1[q*3 + 2] = load_afrag(w_hh_l0 + (size_t)g*HH + 32 + quad*8);
        A2[q*4 + 0] = load_afrag(w_ih_l1 + (size_t)g*HH + quad*8);
        A2[q*4 + 1] = load_afrag(w_ih_l1 + (size_t)g*HH + 32 + quad*8);
        A2[q*4 + 2] = load_afrag(w_hh_l1 + (size_t)g*HH + quad*8);
        A2[q*4 + 3] = load_afrag(w_hh_l1 + (size_t)g*HH + 32 + quad*8);
    }
    b10 = b_ih_l0[0*64 + jj] + b_hh_l0[0*64 + jj];
    b11 = b_ih_l0[1*64 + jj] + b_hh_l0[1*64 + jj];
    b12 = b_ih_l0[2*64 + jj] + b_hh_l0[2*64 + jj];
    b13 = b_ih_l0[3*64 + jj] + b_hh_l0[3*64 + jj];
    b20 = b_ih_l1[0*64 + jj] + b_hh_l1[0*64 + jj];
    b21 = b_ih_l1[1*64 + jj] + b_hh_l1[1*64 + jj];
    b22 = b_ih_l1[2*64 + jj] + b_hh_l1[2*64 + jj];
    b23 = b_ih_l1[3*64 + jj] + b_hh_l1[3*64 + jj];

    // LDS offsets (f16 units)
    const int roff  = (bb*4 + quad)*8;
    const int woff1 = (((1 + (jj >> 5))*4 + bb)*4 + ((jj & 31) >> 3))*8 + (jj & 7);
    const int woff2 = (((3 + (jj >> 5))*4 + bb)*4 + ((jj & 31) >> 3))*8 + (jj & 7);

    // x stager (wave 3): lane -> (batch = lane>>4, k-pair = lane&15)
    const float* xg = x + (size_t)(bbase + (lane >> 4)) * (TT*DD) + (lane & 15)*2;
    const int sdw = ((lane >> 4)*4 + ((lane & 15) >> 2))*4 + ((lane & 15) & 3);
    float2 xv1 = {0.f, 0.f}, xv2 = {0.f, 0.f};

    __syncthreads();
    if (wave == 3) {
        float2 v0 = *(const float2*)xg;                       // x(0)
        ((int*)buf)[sdw] = __builtin_bit_cast(int, pk(v0.x, v0.y));
        xv1 = *(const float2*)(xg + DD);                      // x(1)
        xv2 = *(const float2*)(xg + 2*DD);                    // x(2)
    }
    __syncthreads();

    const bool s0 = (rsel & 1) != 0;
    const bool s1 = (rsel & 2) != 0;
    float c1 = 0.0f, c2 = 0.0f;
    const f32x4 Z = {0.f, 0.f, 0.f, 0.f};

    for (int t = 0; t <= TT; ++t) {
        const int p = t & 1;
        const __fp16* bc = buf + p*640;
        __fp16* bn = buf + (p ^ 1)*640;

        // h1 fragments: shared by both layers
        f16x8 B1 = *(const f16x8*)(bc + 1*128 + roff);
        f16x8 B2 = *(const f16x8*)(bc + 2*128 + roff);

        if (wave == 3 && t < TT) {       // stage x(t+1) into next buffer
            ((int*)bn)[sdw] = __builtin_bit_cast(int, pk(xv1.x, xv1.y));
            xv1 = xv2;
            const int tl = (t + 3 < TT) ? (t + 3) : (TT - 1);
            xv2 = *(const float2*)(xg + (size_t)tl*DD);
        }

        if (t < TT) {   // ---- layer 1: h1(t) ----
            f16x8 B0 = *(const f16x8*)(bc + 0*128 + roff);
            f32x4 C0 = Z, C1f = Z, C2f = Z, C3f = Z;
            C0  = MFMA16(A1[0], B0, C0);  C0  = MFMA16(A1[1],  B1, C0);  C0  = MFMA16(A1[2],  B2, C0);
            C1f = MFMA16(A1[3], B0, C1f); C1f = MFMA16(A1[4],  B1, C1f); C1f = MFMA16(A1[5],  B2, C1f);
            C2f = MFMA16(A1[6], B0, C2f); C2f = MFMA16(A1[7],  B1, C2f); C2f = MFMA16(A1[8],  B2, C2f);
            C3f = MFMA16(A1[9], B0, C3f); C3f = MFMA16(A1[10], B1, C3f); C3f = MFMA16(A1[11], B2, C3f);

            float Si = pick4(C0,  s0, s1) + b10;
            float Sf = pick4(C1f, s0, s1) + b11;
            float Sg = pick4(C2f, s0, s1) + b12;
            float So = pick4(C3f, s0, s1) + b13;

            float ii = fsig(Si), ff = fsig(Sf), oo = fsig(So);
            float gg = ftanh(Sg);
            c1 = ff * c1 + ii * gg;
            float hv = oo * ftanh(c1);
            bn[woff1] = (__fp16)hv;
        }

        if (t > 0) {    // ---- layer 2: h2(t-1) ----
            f16x8 B3 = *(const f16x8*)(bc + 3*128 + roff);
            f16x8 B4 = *(const f16x8*)(bc + 4*128 + roff);
            f32x4 D0 = Z, D1 = Z, D2 = Z, D3 = Z;
            D0 = MFMA16(A2[0],  B1, D0); D0 = MFMA16(A2[1],  B2, D0);
            D0 = MFMA16(A2[2],  B3, D0); D0 = MFMA16(A2[3],  B4, D0);
            D1 = MFMA16(A2[4],  B1, D1); D1 = MFMA16(A2[5],  B2, D1);
            D1 = MFMA16(A2[6],  B3, D1); D1 = MFMA16(A2[7],  B4, D1);
            D2 = MFMA16(A2[8],  B1, D2); D2 = MFMA16(A2[9],  B2, D2);
            D2 = MFMA16(A2[10], B3, D2); D2 = MFMA16(A2[11], B4, D2);
            D3 = MFMA16(A2[12], B1, D3); D3 = MFMA16(A2[13], B2, D3);
            D3 = MFMA16(A2[14], B3, D3); D3 = MFMA16(A2[15], B4, D3);

            float Si = pick4(D0, s0, s1) + b20;
            float Sf = pick4(D1, s0, s1) + b21;
            float Sg = pick4(D2, s0, s1) + b22;
            float So = pick4(D3, s0, s1) + b23;

            float ii = fsig(Si), ff = fsig(Sf), oo = fsig(So);
            float gg = ftanh(Sg);
            c2 = ff * c2 + ii * gg;
            float hv = oo * ftanh(c2);
            bn[woff2] = (__fp16)hv;
        }

        bar_lds();
    }

    // h2(TT-1) sits in parity 1, chunks 3,4. FC + sigmoid (wave 0).
    if (wave == 0) {
        const int jg = lane >> 2;   // 0..15
        float s = 0.f;
        #pragma unroll
        for (int u2 = 0; u2 < 4; ++u2) {
            const int j = jg*4 + u2;
            float hval = (float)buf[640 + (((3 + (j >> 5))*4 + bb)*4 + ((j & 31) >> 3))*8 + (j & 7)];
            s += hval * w_fc[j];
        }
        s += __shfl_xor(s, 4);
        s += __shfl_xor(s, 8);
        s += __shfl_xor(s, 16);
        s += __shfl_xor(s, 32);
        if (lane < 4) out[bbase + lane] = fsig(s + b_fc[0]);
    }
}

extern "C" void kernel_launch(void* const* d_in, const int* in_sizes, int n_in,
                              void* d_out, int out_size, void* d_ws, size_t ws_size,
                              hipStream_t stream) {
    lstm2_m4<<<dim3(64), dim3(256), 0, stream>>>(
        (const float*)d_in[0],
        (const float*)d_in[1], (const float*)d_in[2],
        (const float*)d_in[3], (const float*)d_in[4],
        (const float*)d_in[5], (const float*)d_in[6],
        (const float*)d_in[7], (const float*)d_in[8],
        (const float*)d_in[9], (const float*)d_in[10],
        (float*)d_out);
}

// Round 16
// 579.705 us; speedup vs baseline: 1.5272x; 1.5272x over previous
//
#include <hip/hip_runtime.h>

#define TT 1024
#define DD 32
#define HH 64

typedef __fp16 h2v __attribute__((ext_vector_type(2)));
typedef _Float16 f16x8 __attribute__((ext_vector_type(8)));
typedef float f32x4 __attribute__((ext_vector_type(4)));

struct __attribute__((aligned(16))) H4 { h2v p[4]; };

__device__ __forceinline__ h2v pk(float a, float b) {
    return __builtin_amdgcn_cvt_pkrtz(a, b);
}
__device__ __forceinline__ float fsig(float x) {
    float e = __builtin_amdgcn_exp2f(-1.4426950408889634f * x);
    return __builtin_amdgcn_rcpf(1.0f + e);
}
__device__ __forceinline__ float ftanh(float x) {
    float e = __builtin_amdgcn_exp2f(2.885390081777927f * x);
    return 1.0f - 2.0f * __builtin_amdgcn_rcpf(1.0f + e);
}
// select reg r (r = s1*2+s0) of a C-fragment: 3 cndmasks
__device__ __forceinline__ float pick4(f32x4 c, bool s0, bool s1) {
    float lo = s0 ? c[1] : c[0];
    float hi = s0 ? c[3] : c[2];
    return s1 ? hi : lo;
}
// A-fragment: 8 consecutive fp32 weights -> packed f16 (lane = A[m=lane&15][k=quad*8+i])
__device__ __forceinline__ f16x8 load_afrag(const float* p) {
    float4 f0 = *(const float4*)p;
    float4 f1 = *(const float4*)(p + 4);
    H4 t;
    t.p[0] = pk(f0.x, f0.y); t.p[1] = pk(f0.z, f0.w);
    t.p[2] = pk(f1.x, f1.y); t.p[3] = pk(f1.z, f1.w);
    return __builtin_bit_cast(f16x8, t);
}
#define MFMA16(A, B, C) __builtin_amdgcn_mfma_f32_16x16x32_f16(A, B, C, 0, 0, 0)

// ---------------------------------------------------------------------------
// EXACT R12 structure (best verified: 545 us total) with ONE change:
// dependent MFMA chains split L1 3->2+1, L2 4->2+2 (combined after pick4),
// removing 1-2 dependent-MFMA latencies from the per-step serial chain.
//
// 64 blocks x 512 threads; block = 4 batch elements.
// Waves 0-3: L1 (j-slice = wave). Waves 4-7: L2 (one step behind); wave 7
// stages x(t+1) into LDS (fp32->f16) with a 2-deep register prefetch ring.
// LDS per parity: 5 chunks x [batch4][quad4][8 f16]:
//   chunk 0 = x(t), chunks 1,2 = h1(t-1), chunks 3,4 = h2(t-2)
// B cols = 4 batches x 4 reps (col&3 = batch). C layout (m89): col=lane&15,
// row=quad*4+reg -> lane owns unique cell (j=js*16+quad*4+rsel, batch=lane&3).
// ---------------------------------------------------------------------------
__global__ __launch_bounds__(512) void lstm2_b4s(
    const float* __restrict__ x,
    const float* __restrict__ w_ih_l0, const float* __restrict__ w_hh_l0,
    const float* __restrict__ b_ih_l0, const float* __restrict__ b_hh_l0,
    const float* __restrict__ w_ih_l1, const float* __restrict__ w_hh_l1,
    const float* __restrict__ b_ih_l1, const float* __restrict__ b_hh_l1,
    const float* __restrict__ w_fc,   const float* __restrict__ b_fc,
    float* __restrict__ out)
{
    const int bbase = blockIdx.x * 4;
    const int tid  = threadIdx.x;
    const int wave = tid >> 6;
    const int lane = tid & 63;
    const bool isL1 = wave < 4;
    const int js   = wave & 3;
    const int quad = lane >> 4;
    const int bb   = lane & 3;
    const int rsel = (lane >> 2) & 3;
    const int jj   = js*16 + quad*4 + rsel;
    const int mrow = lane & 15;

    __shared__ __attribute__((aligned(16))) __fp16 buf[1280];  // [2][5][4][4][8]

    {
        int* bi = (int*)buf;
        bi[tid] = 0;
        if (tid < 128) bi[512 + tid] = 0;
    }

    // ---- A fragments (weights), biases ----
    f16x8 A[16];
    float bs0, bs1, bs2, bs3;
    if (isL1) {
        #pragma unroll
        for (int q = 0; q < 4; ++q) {
            const int g = q*64 + js*16 + mrow;
            A[q*3 + 0] = load_afrag(w_ih_l0 + (size_t)g*DD + quad*8);
            A[q*3 + 1] = load_afrag(w_hh_l0 + (size_t)g*HH + quad*8);
            A[q*3 + 2] = load_afrag(w_hh_l0 + (size_t)g*HH + 32 + quad*8);
        }
        bs0 = b_ih_l0[0*64 + jj] + b_hh_l0[0*64 + jj];
        bs1 = b_ih_l0[1*64 + jj] + b_hh_l0[1*64 + jj];
        bs2 = b_ih_l0[2*64 + jj] + b_hh_l0[2*64 + jj];
        bs3 = b_ih_l0[3*64 + jj] + b_hh_l0[3*64 + jj];
    } else {
        #pragma unroll
        for (int q = 0; q < 4; ++q) {
            const int g = q*64 + js*16 + mrow;
            A[q*4 + 0] = load_afrag(w_ih_l1 + (size_t)g*HH + quad*8);
            A[q*4 + 1] = load_afrag(w_ih_l1 + (size_t)g*HH + 32 + quad*8);
            A[q*4 + 2] = load_afrag(w_hh_l1 + (size_t)g*HH + quad*8);
            A[q*4 + 3] = load_afrag(w_hh_l1 + (size_t)g*HH + 32 + quad*8);
        }
        bs0 = b_ih_l1[0*64 + jj] + b_hh_l1[0*64 + jj];
        bs1 = b_ih_l1[1*64 + jj] + b_hh_l1[1*64 + jj];
        bs2 = b_ih_l1[2*64 + jj] + b_hh_l1[2*64 + jj];
        bs3 = b_ih_l1[3*64 + jj] + b_hh_l1[3*64 + jj];
    }

    // per-lane LDS offsets (f16 units)
    const int roff = (bb*4 + quad)*8;
    const int cw   = (isL1 ? 1 : 3) + (jj >> 5);
    const int woff = ((cw*4 + bb)*4 + ((jj & 31) >> 3))*8 + (jj & 7);

    // x stager (wave 7): lane -> (batch = lane>>4, k-pair = lane&15)
    const float* xg = x + (size_t)(bbase + (lane >> 4)) * (TT*DD) + (lane & 15)*2;
    const int sdw = ((lane >> 4)*4 + ((lane & 15) >> 2))*4 + ((lane & 15) & 3);
    float2 xv1 = {0.f, 0.f}, xv2 = {0.f, 0.f};

    __syncthreads();   // zero-init visible before x(0) staging
    if (wave == 7) {
        float2 v0 = *(const float2*)xg;                       // x(0)
        ((int*)buf)[sdw] = __builtin_bit_cast(int, pk(v0.x, v0.y));
        xv1 = *(const float2*)(xg + DD);                      // x(1)
        xv2 = *(const float2*)(xg + 2*DD);                    // x(2)
    }
    __syncthreads();

    const bool s0 = (rsel & 1) != 0;
    const bool s1 = (rsel & 2) != 0;
    float cst = 0.0f;
    const f32x4 Z = {0.f, 0.f, 0.f, 0.f};

    for (int t = 0; t <= TT; ++t) {
        const int p = t & 1;
        const __fp16* bc = buf + p*640;
        __fp16* bn = buf + (p ^ 1)*640;
        if (isL1) {
            if (t < TT) {
                f16x8 B0 = *(const f16x8*)(bc + 0*128 + roff);
                f16x8 B1 = *(const f16x8*)(bc + 1*128 + roff);
                f16x8 B2 = *(const f16x8*)(bc + 2*128 + roff);

                // split chains: 2-deep (B0,B1) + 1-deep (B2)
                f32x4 C0 = MFMA16(A[0], B0, Z); C0 = MFMA16(A[1],  B1, C0);
                f32x4 C1 = MFMA16(A[3], B0, Z); C1 = MFMA16(A[4],  B1, C1);
                f32x4 C2 = MFMA16(A[6], B0, Z); C2 = MFMA16(A[7],  B1, C2);
                f32x4 C3 = MFMA16(A[9], B0, Z); C3 = MFMA16(A[10], B1, C3);
                f32x4 D0 = MFMA16(A[2],  B2, Z);
                f32x4 D1 = MFMA16(A[5],  B2, Z);
                f32x4 D2 = MFMA16(A[8],  B2, Z);
                f32x4 D3 = MFMA16(A[11], B2, Z);

                float Si = pick4(C0, s0, s1) + pick4(D0, s0, s1) + bs0;
                float Sf = pick4(C1, s0, s1) + pick4(D1, s0, s1) + bs1;
                float Sg = pick4(C2, s0, s1) + pick4(D2, s0, s1) + bs2;
                float So = pick4(C3, s0, s1) + pick4(D3, s0, s1) + bs3;

                float ii = fsig(Si), ff = fsig(Sf), oo = fsig(So);
                float gg = ftanh(Sg);
                cst = ff * cst + ii * gg;
                float hv = oo * ftanh(cst);
                bn[woff] = (__fp16)hv;
            }
        } else {
            if (wave == 7 && t < TT) {   // stage x(t+1) into next buffer
                ((int*)bn)[sdw] = __builtin_bit_cast(int, pk(xv1.x, xv1.y));
                xv1 = xv2;
                const int tl = (t + 3 < TT) ? (t + 3) : (TT - 1);
                xv2 = *(const float2*)(xg + (size_t)tl*DD);
            }
            if (t > 0) {
                f16x8 B1 = *(const f16x8*)(bc + 1*128 + roff);
                f16x8 B2 = *(const f16x8*)(bc + 2*128 + roff);
                f16x8 B3 = *(const f16x8*)(bc + 3*128 + roff);
                f16x8 B4 = *(const f16x8*)(bc + 4*128 + roff);

                // split chains: 2-deep (B1,B2) + 2-deep (B3,B4)
                f32x4 C0 = MFMA16(A[0],  B1, Z); C0 = MFMA16(A[1],  B2, C0);
                f32x4 C1 = MFMA16(A[4],  B1, Z); C1 = MFMA16(A[5],  B2, C1);
                f32x4 C2 = MFMA16(A[8],  B1, Z); C2 = MFMA16(A[9],  B2, C2);
                f32x4 C3 = MFMA16(A[12], B1, Z); C3 = MFMA16(A[13], B2, C3);
                f32x4 D0 = MFMA16(A[2],  B3, Z); D0 = MFMA16(A[3],  B4, D0);
                f32x4 D1 = MFMA16(A[6],  B3, Z); D1 = MFMA16(A[7],  B4, D1);
                f32x4 D2 = MFMA16(A[10], B3, Z); D2 = MFMA16(A[11], B4, D2);
                f32x4 D3 = MFMA16(A[14], B3, Z); D3 = MFMA16(A[15], B4, D3);

                float Si = pick4(C0, s0, s1) + pick4(D0, s0, s1) + bs0;
                float Sf = pick4(C1, s0, s1) + pick4(D1, s0, s1) + bs1;
                float Sg = pick4(C2, s0, s1) + pick4(D2, s0, s1) + bs2;
                float So = pick4(C3, s0, s1) + pick4(D3, s0, s1) + bs3;

                float ii = fsig(Si), ff = fsig(Sf), oo = fsig(So);
                float gg = ftanh(Sg);
                cst = ff * cst + ii * gg;
                float hv = oo * ftanh(cst);
                bn[woff] = (__fp16)hv;
            }
        }
        __syncthreads();
    }

    // h2(TT-1) sits in buf parity 1, chunks 3,4. FC + sigmoid (wave 0).
    if (wave == 0) {
        const int jg = lane >> 2;   // 0..15
        float s = 0.f;
        #pragma unroll
        for (int u2 = 0; u2 < 4; ++u2) {
            const int j = jg*4 + u2;
            float hval = (float)buf[640 + (((3 + (j >> 5))*4 + bb)*4 + ((j & 31) >> 3))*8 + (j & 7)];
            s += hval * w_fc[j];
        }
        s += __shfl_xor(s, 4);
        s += __shfl_xor(s, 8);
        s += __shfl_xor(s, 16);
        s += __shfl_xor(s, 32);
        if (lane < 4) out[bbase + lane] = fsig(s + b_fc[0]);
    }
}

extern "C" void kernel_launch(void* const* d_in, const int* in_sizes, int n_in,
                              void* d_out, int out_size, void* d_ws, size_t ws_size,
                              hipStream_t stream) {
    lstm2_b4s<<<dim3(64), dim3(512), 0, stream>>>(
        (const float*)d_in[0],
        (const float*)d_in[1], (const float*)d_in[2],
        (const float*)d_in[3], (const float*)d_in[4],
        (const float*)d_in[5], (const float*)d_in[6],
        (const float*)d_in[7], (const float*)d_in[8],
        (const float*)d_in[9], (const float*)d_in[10],
        (float*)d_out);
}

// Round 17
// 544.804 us; speedup vs baseline: 1.6250x; 1.0641x over previous
//
#include <hip/hip_runtime.h>

#define TT 1024
#define DD 32
#define HH 64

typedef __fp16 h2v __attribute__((ext_vector_type(2)));
typedef _Float16 f16x8 __attribute__((ext_vector_type(8)));
typedef float f32x4 __attribute__((ext_vector_type(4)));

struct __attribute__((aligned(16))) H4 { h2v p[4]; };

__device__ __forceinline__ h2v pk(float a, float b) {
    return __builtin_amdgcn_cvt_pkrtz(a, b);
}
__device__ __forceinline__ float fsig(float x) {
    float e = __builtin_amdgcn_exp2f(-1.4426950408889634f * x);
    return __builtin_amdgcn_rcpf(1.0f + e);
}
__device__ __forceinline__ float ftanh(float x) {
    float e = __builtin_amdgcn_exp2f(2.885390081777927f * x);
    return 1.0f - 2.0f * __builtin_amdgcn_rcpf(1.0f + e);
}
// select reg r (r = s1*2+s0) of a C-fragment: 3 cndmasks
__device__ __forceinline__ float pick4(f32x4 c, bool s0, bool s1) {
    float lo = s0 ? c[1] : c[0];
    float hi = s0 ? c[3] : c[2];
    return s1 ? hi : lo;
}
// A-fragment: 8 consecutive fp32 weights -> packed f16 (lane = A[m=lane&15][k=quad*8+i])
__device__ __forceinline__ f16x8 load_afrag(const float* p) {
    float4 f0 = *(const float4*)p;
    float4 f1 = *(const float4*)(p + 4);
    H4 t;
    t.p[0] = pk(f0.x, f0.y); t.p[1] = pk(f0.z, f0.w);
    t.p[2] = pk(f1.x, f1.y); t.p[3] = pk(f1.z, f1.w);
    return __builtin_bit_cast(f16x8, t);
}
#define MFMA16(A, B, C) __builtin_amdgcn_mfma_f32_16x16x32_f16(A, B, C, 0, 0, 0)

// ---------------------------------------------------------------------------
// FINAL: exact R12 kernel — verified best (545 us total).
// Per-step wall (~1140 cyc) is the latency floor of the cross-wave skewed
// pipeline: barrier sync (~300) + LDS round-trip (~200) + MFMA chain (~90)
// + activation chain (~120) + DS-pipe occupancy (~250). Falsified theories:
// issue load (R12), bank conflicts (R9), vmcnt drain (R11/R14), MFMA chain
// depth (R16), barrier participants (R15 — layer merge serializes chains).
//
// 64 blocks x 512 threads; block = 4 batch elements.
// Waves 0-3: L1 (j-slice = wave). Waves 4-7: L2 (one step behind); wave 7
// stages x(t+1) into LDS (fp32->f16) with a 2-deep register prefetch ring.
// LDS per parity: 5 chunks x [batch4][quad4][8 f16]:
//   chunk 0 = x(t), chunks 1,2 = h1(t-1), chunks 3,4 = h2(t-2)
// B cols = 4 batches x 4 reps (col&3 = batch). C layout (m89): col=lane&15,
// row=quad*4+reg -> lane owns unique cell (j=js*16+quad*4+rsel, batch=lane&3).
// Weights are MFMA-A-operands only -> AGPR-resident at zero copy cost.
// ---------------------------------------------------------------------------
__global__ __launch_bounds__(512) void lstm2_b4(
    const float* __restrict__ x,
    const float* __restrict__ w_ih_l0, const float* __restrict__ w_hh_l0,
    const float* __restrict__ b_ih_l0, const float* __restrict__ b_hh_l0,
    const float* __restrict__ w_ih_l1, const float* __restrict__ w_hh_l1,
    const float* __restrict__ b_ih_l1, const float* __restrict__ b_hh_l1,
    const float* __restrict__ w_fc,   const float* __restrict__ b_fc,
    float* __restrict__ out)
{
    const int bbase = blockIdx.x * 4;
    const int tid  = threadIdx.x;
    const int wave = tid >> 6;
    const int lane = tid & 63;
    const bool isL1 = wave < 4;
    const int js   = wave & 3;
    const int quad = lane >> 4;
    const int bb   = lane & 3;
    const int rsel = (lane >> 2) & 3;
    const int jj   = js*16 + quad*4 + rsel;
    const int mrow = lane & 15;

    __shared__ __attribute__((aligned(16))) __fp16 buf[1280];  // [2][5][4][4][8]

    {
        int* bi = (int*)buf;
        bi[tid] = 0;
        if (tid < 128) bi[512 + tid] = 0;
    }

    // ---- A fragments (weights), biases ----
    f16x8 A[16];
    float bs0, bs1, bs2, bs3;
    if (isL1) {
        #pragma unroll
        for (int q = 0; q < 4; ++q) {
            const int g = q*64 + js*16 + mrow;
            A[q*3 + 0] = load_afrag(w_ih_l0 + (size_t)g*DD + quad*8);
            A[q*3 + 1] = load_afrag(w_hh_l0 + (size_t)g*HH + quad*8);
            A[q*3 + 2] = load_afrag(w_hh_l0 + (size_t)g*HH + 32 + quad*8);
        }
        bs0 = b_ih_l0[0*64 + jj] + b_hh_l0[0*64 + jj];
        bs1 = b_ih_l0[1*64 + jj] + b_hh_l0[1*64 + jj];
        bs2 = b_ih_l0[2*64 + jj] + b_hh_l0[2*64 + jj];
        bs3 = b_ih_l0[3*64 + jj] + b_hh_l0[3*64 + jj];
    } else {
        #pragma unroll
        for (int q = 0; q < 4; ++q) {
            const int g = q*64 + js*16 + mrow;
            A[q*4 + 0] = load_afrag(w_ih_l1 + (size_t)g*HH + quad*8);
            A[q*4 + 1] = load_afrag(w_ih_l1 + (size_t)g*HH + 32 + quad*8);
            A[q*4 + 2] = load_afrag(w_hh_l1 + (size_t)g*HH + quad*8);
            A[q*4 + 3] = load_afrag(w_hh_l1 + (size_t)g*HH + 32 + quad*8);
        }
        bs0 = b_ih_l1[0*64 + jj] + b_hh_l1[0*64 + jj];
        bs1 = b_ih_l1[1*64 + jj] + b_hh_l1[1*64 + jj];
        bs2 = b_ih_l1[2*64 + jj] + b_hh_l1[2*64 + jj];
        bs3 = b_ih_l1[3*64 + jj] + b_hh_l1[3*64 + jj];
    }

    // per-lane LDS offsets (f16 units)
    const int roff = (bb*4 + quad)*8;
    const int cw   = (isL1 ? 1 : 3) + (jj >> 5);
    const int woff = ((cw*4 + bb)*4 + ((jj & 31) >> 3))*8 + (jj & 7);

    // x stager (wave 7): lane -> (batch = lane>>4, k-pair = lane&15)
    const float* xg = x + (size_t)(bbase + (lane >> 4)) * (TT*DD) + (lane & 15)*2;
    const int sdw = ((lane >> 4)*4 + ((lane & 15) >> 2))*4 + ((lane & 15) & 3);
    float2 xv1 = {0.f, 0.f}, xv2 = {0.f, 0.f};

    __syncthreads();   // zero-init visible before x(0) staging
    if (wave == 7) {
        float2 v0 = *(const float2*)xg;                       // x(0)
        ((int*)buf)[sdw] = __builtin_bit_cast(int, pk(v0.x, v0.y));
        xv1 = *(const float2*)(xg + DD);                      // x(1)
        xv2 = *(const float2*)(xg + 2*DD);                    // x(2)
    }
    __syncthreads();

    const bool s0 = (rsel & 1) != 0;
    const bool s1 = (rsel & 2) != 0;
    float cst = 0.0f;

    for (int t = 0; t <= TT; ++t) {
        const int p = t & 1;
        const __fp16* bc = buf + p*640;
        __fp16* bn = buf + (p ^ 1)*640;
        if (isL1) {
            if (t < TT) {
                f16x8 B0 = *(const f16x8*)(bc + 0*128 + roff);
                f16x8 B1 = *(const f16x8*)(bc + 1*128 + roff);
                f16x8 B2 = *(const f16x8*)(bc + 2*128 + roff);

                f32x4 Z = {0.f, 0.f, 0.f, 0.f};
                f32x4 C0 = Z, C1 = Z, C2 = Z, C3 = Z;
                C0 = MFMA16(A[0], B0, C0); C0 = MFMA16(A[1],  B1, C0); C0 = MFMA16(A[2],  B2, C0);
                C1 = MFMA16(A[3], B0, C1); C1 = MFMA16(A[4],  B1, C1); C1 = MFMA16(A[5],  B2, C1);
                C2 = MFMA16(A[6], B0, C2); C2 = MFMA16(A[7],  B1, C2); C2 = MFMA16(A[8],  B2, C2);
                C3 = MFMA16(A[9], B0, C3); C3 = MFMA16(A[10], B1, C3); C3 = MFMA16(A[11], B2, C3);

                float Si = pick4(C0, s0, s1) + bs0;
                float Sf = pick4(C1, s0, s1) + bs1;
                float Sg = pick4(C2, s0, s1) + bs2;
                float So = pick4(C3, s0, s1) + bs3;

                float ii = fsig(Si), ff = fsig(Sf), oo = fsig(So);
                float gg = ftanh(Sg);
                cst = ff * cst + ii * gg;
                float hv = oo * ftanh(cst);
                bn[woff] = (__fp16)hv;
            }
        } else {
            if (wave == 7 && t < TT) {   // stage x(t+1) into next buffer
                ((int*)bn)[sdw] = __builtin_bit_cast(int, pk(xv1.x, xv1.y));
                xv1 = xv2;
                const int tl = (t + 3 < TT) ? (t + 3) : (TT - 1);
                xv2 = *(const float2*)(xg + (size_t)tl*DD);
            }
            if (t > 0) {
                f16x8 B1 = *(const f16x8*)(bc + 1*128 + roff);
                f16x8 B2 = *(const f16x8*)(bc + 2*128 + roff);
                f16x8 B3 = *(const f16x8*)(bc + 3*128 + roff);
                f16x8 B4 = *(const f16x8*)(bc + 4*128 + roff);

                f32x4 Z = {0.f, 0.f, 0.f, 0.f};
                f32x4 C0 = Z, C1 = Z, C2 = Z, C3 = Z;
                C0 = MFMA16(A[0],  B1, C0); C0 = MFMA16(A[1],  B2, C0);
                C0 = MFMA16(A[2],  B3, C0); C0 = MFMA16(A[3],  B4, C0);
                C1 = MFMA16(A[4],  B1, C1); C1 = MFMA16(A[5],  B2, C1);
                C1 = MFMA16(A[6],  B3, C1); C1 = MFMA16(A[7],  B4, C1);
                C2 = MFMA16(A[8],  B1, C2); C2 = MFMA16(A[9],  B2, C2);
                C2 = MFMA16(A[10], B3, C2); C2 = MFMA16(A[11], B4, C2);
                C3 = MFMA16(A[12], B1, C3); C3 = MFMA16(A[13], B2, C3);
                C3 = MFMA16(A[14], B3, C3); C3 = MFMA16(A[15], B4, C3);

                float Si = pick4(C0, s0, s1) + bs0;
                float Sf = pick4(C1, s0, s1) + bs1;
                float Sg = pick4(C2, s0, s1) + bs2;
                float So = pick4(C3, s0, s1) + bs3;

                float ii = fsig(Si), ff = fsig(Sf), oo = fsig(So);
                float gg = ftanh(Sg);
                cst = ff * cst + ii * gg;
                float hv = oo * ftanh(cst);
                bn[woff] = (__fp16)hv;
            }
        }
        __syncthreads();
    }

    // h2(TT-1) sits in buf parity 1, chunks 3,4. FC + sigmoid (wave 0).
    if (wave == 0) {
        const int jg = lane >> 2;   // 0..15
        float s = 0.f;
        #pragma unroll
        for (int u2 = 0; u2 < 4; ++u2) {
            const int j = jg*4 + u2;
            float hval = (float)buf[640 + (((3 + (j >> 5))*4 + bb)*4 + ((j & 31) >> 3))*8 + (j & 7)];
            s += hval * w_fc[j];
        }
        s += __shfl_xor(s, 4);
        s += __shfl_xor(s, 8);
        s += __shfl_xor(s, 16);
        s += __shfl_xor(s, 32);
        if (lane < 4) out[bbase + lane] = fsig(s + b_fc[0]);
    }
}

extern "C" void kernel_launch(void* const* d_in, const int* in_sizes, int n_in,
                              void* d_out, int out_size, void* d_ws, size_t ws_size,
                              hipStream_t stream) {
    lstm2_b4<<<dim3(64), dim3(512), 0, stream>>>(
        (const float*)d_in[0],
        (const float*)d_in[1], (const float*)d_in[2],
        (const float*)d_in[3], (const float*)d_in[4],
        (const float*)d_in[5], (const float*)d_in[6],
        (const float*)d_in[7], (const float*)d_in[8],
        (const float*)d_in[9], (const float*)d_in[10],
        (float*)d_out);
}